// Round 7
// baseline (287.124 us; speedup 1.0000x reference)
//
#include <hip/hip_runtime.h>
#include <math.h>

#define NEG_SLOPE 0.2f
#define EPS_DEN 1e-16f

typedef __attribute__((ext_vector_type(8))) short bf16x8;
typedef __attribute__((ext_vector_type(4))) float f32x4;

__device__ inline void split2(float a, short& hi, short& lo) {
    unsigned u = __float_as_uint(a);
    unsigned uh = (u + 0x8000u) & 0xFFFF0000u;
    float fh = __uint_as_float(uh);
    hi = (short)(uh >> 16);
    float r = a - fh;
    lo = (short)((__float_as_uint(r) + 0x8000u) >> 16);
}

__device__ inline unsigned short f2bf(float f) {   // RNE
    unsigned u = __float_as_uint(f);
    return (unsigned short)((u + 0x7FFFu + ((u >> 16) & 1u)) >> 16);
}
__device__ inline float bflo(unsigned u) { return __uint_as_float(u << 16); }
__device__ inline float bfhi(unsigned u) { return __uint_as_float(u & 0xFFFF0000u); }

// ---------------- CSR build ----------------
__global__ void k_count(const int* __restrict__ ei, int E, int Nn, int* counts) {
    int e = blockIdx.x * blockDim.x + threadIdx.x;
    int ET = E + Nn;
    if (e >= ET) return;
    int d = (e < E) ? ei[E + e] : (e - E);
    atomicAdd(&counts[d], 1);
}

__global__ void k_scan(const int* __restrict__ counts, int Nn, int ET, int* __restrict__ row_off) {
    __shared__ int lds[256];
    int t = threadIdx.x;
    int chunk = (Nn + 255) / 256;
    int b0 = t * chunk, b1 = min(Nn, b0 + chunk);
    int s = 0;
    for (int i = b0; i < b1; i++) s += counts[i];
    lds[t] = s;
    __syncthreads();
    if (t == 0) {
        int run = 0;
        for (int i = 0; i < 256; i++) { int v = lds[i]; lds[i] = run; run += v; }
    }
    __syncthreads();
    int run = lds[t];
    for (int i = b0; i < b1; i++) { row_off[i] = run; run += counts[i]; }
    if (t == 0) row_off[Nn] = ET;
}

__global__ void k_scatter(const int* __restrict__ ei, int E, int Nn,
                          const int* __restrict__ row_off, int* cursor, int* __restrict__ col) {
    int e = blockIdx.x * blockDim.x + threadIdx.x;
    int ET = E + Nn;
    if (e >= ET) return;
    int d = (e < E) ? ei[E + e] : (e - E);
    int s = (e < E) ? ei[e] : (e - E);
    int pos = atomicAdd(&cursor[d], 1);
    col[row_off[d] + pos] = s;
}

// ---------------- split conversions ----------------
__global__ void k_split_x(const float* __restrict__ x, short* __restrict__ A,
                          int M, int Mp, int K) {
    int i = blockIdx.x * blockDim.x + threadIdx.x;
    if (i >= Mp * K) return;
    int row = i / K, c = i - row * K;
    float v = (row < M) ? x[(size_t)row * K + c] : 0.f;
    short hi, lo;
    split2(v, hi, lo);
    A[(size_t)row * (2 * K) + c] = hi;
    A[(size_t)row * (2 * K) + K + c] = lo;
}

// W [K,N] f32 -> Bt [N, (1+dup)K] bf16 (transposed; dup=1 writes [hi|hi] for split-A GEMM)
__global__ __launch_bounds__(256) void k_split_wt(const float* __restrict__ W,
                                                  short* __restrict__ Bt, int K, int N, int dup) {
    __shared__ float s[32][33];
    int k0 = blockIdx.x * 32, n0 = blockIdx.y * 32;
    int tx = threadIdx.x & 31, ty = threadIdx.x >> 5;
    for (int r = ty; r < 32; r += 8) s[r][tx] = W[(size_t)(k0 + r) * N + n0 + tx];
    __syncthreads();
    int ldbt = (1 + dup) * K;
    for (int r = ty; r < 32; r += 8) {
        float v = s[tx][r];
        unsigned u = __float_as_uint(v);
        short hi = (short)((u + 0x7FFFu + ((u >> 16) & 1u)) >> 16);
        size_t base = (size_t)(n0 + r) * ldbt + k0 + tx;
        Bt[base] = hi;
        if (dup) Bt[base + K] = hi;
    }
}

// ---------------- MFMA bf16 GEMM, 64x64 tile, BK=32, fused attention scores ----------------
// C[M,N](bf16) = A[M,Ktot] x Bt[N,Ktot]; also atomically accumulates
// ssrc[r*H+hh] += sum_col h[r][col]*a_src[col], sdst likewise. hh = col >> lc2.
__global__ __launch_bounds__(256) void k_mfma64(const short* __restrict__ A,
                                                const short* __restrict__ B,
                                                unsigned short* __restrict__ C,
                                                const float* __restrict__ a_src,
                                                const float* __restrict__ a_dst,
                                                float* __restrict__ ssrc,
                                                float* __restrict__ sdst,
                                                int M, int N, int Ktot,
                                                int lda, int ldb, int lc2) {
    __shared__ short As[64 * 32];
    __shared__ short Bs[64 * 32];
    int t = threadIdx.x;
    int lane = t & 63;
    int wid = t >> 6;

    int nbx = N >> 6;
    int nb = gridDim.x;
    int q = nb >> 3, r = nb & 7;
    int xcd = blockIdx.x & 7, pos = blockIdx.x >> 3;
    int L = (xcd < r ? xcd * (q + 1) : r * (q + 1) + (xcd - r) * q) + pos;
    int bn = (L % nbx) * 64;
    int bm = (L / nbx) * 64;

    int wm = (wid >> 1) * 32, wn = (wid & 1) * 32;
    int fr = lane & 15, kq = lane >> 4;

    int srow = t >> 2, sslot = t & 3;
    int sko = ((sslot ^ ((srow >> 1) & 3)) << 3);

    f32x4 acc[2][2] = {};

    for (int k0 = 0; k0 < Ktot; k0 += 32) {
        {
            const short* sa = A + (size_t)(bm + srow) * lda + k0 + sko;
            const short* sb = B + (size_t)(bn + srow) * ldb + k0 + sko;
            short* da = As + (size_t)(wid << 6) * 8;
            short* db = Bs + (size_t)(wid << 6) * 8;
            __builtin_amdgcn_global_load_lds((const __attribute__((address_space(1))) void*)sa,
                                             (__attribute__((address_space(3))) void*)da, 16, 0, 0);
            __builtin_amdgcn_global_load_lds((const __attribute__((address_space(1))) void*)sb,
                                             (__attribute__((address_space(3))) void*)db, 16, 0, 0);
        }
        __syncthreads();
        bf16x8 af[2], bfv[2];
        #pragma unroll
        for (int i = 0; i < 2; i++) {
            int rowa = wm + i * 16 + fr;
            int rowb = wn + i * 16 + fr;
            af[i]  = *(const bf16x8*)(As + rowa * 32 + ((kq ^ ((rowa >> 1) & 3)) << 3));
            bfv[i] = *(const bf16x8*)(Bs + rowb * 32 + ((kq ^ ((rowb >> 1) & 3)) << 3));
        }
        #pragma unroll
        for (int i = 0; i < 2; i++)
            #pragma unroll
            for (int j = 0; j < 2; j++)
                acc[i][j] = __builtin_amdgcn_mfma_f32_16x16x32_bf16(af[i], bfv[j], acc[i][j], 0, 0, 0);
        __syncthreads();
    }
    // C write (bf16)
    #pragma unroll
    for (int i = 0; i < 2; i++) {
        int rbase = bm + wm + i * 16 + kq * 4;
        #pragma unroll
        for (int j = 0; j < 2; j++) {
            int colc = bn + wn + j * 16 + fr;
            #pragma unroll
            for (int rg = 0; rg < 4; rg++) {
                int rr = rbase + rg;
                if (rr < M) C[(size_t)rr * N + colc] = f2bf(acc[i][j][rg]);
            }
        }
    }
    // fused partial scores: reduce over this block's 32 cols (all same head)
    float ps[2][4], pd[2][4];
    #pragma unroll
    for (int i = 0; i < 2; i++)
        #pragma unroll
        for (int rg = 0; rg < 4; rg++) { ps[i][rg] = 0.f; pd[i][rg] = 0.f; }
    #pragma unroll
    for (int j = 0; j < 2; j++) {
        int colc = bn + wn + j * 16 + fr;
        float asv = a_src[colc], adv = a_dst[colc];
        #pragma unroll
        for (int i = 0; i < 2; i++)
            #pragma unroll
            for (int rg = 0; rg < 4; rg++) {
                ps[i][rg] += acc[i][j][rg] * asv;
                pd[i][rg] += acc[i][j][rg] * adv;
            }
    }
    int hh = (bn + wn) >> lc2;
    #pragma unroll
    for (int i = 0; i < 2; i++)
        #pragma unroll
        for (int rg = 0; rg < 4; rg++) {
            float sv = ps[i][rg], dv = pd[i][rg];
            #pragma unroll
            for (int off = 8; off >= 1; off >>= 1) {
                sv += __shfl_xor(sv, off);
                dv += __shfl_xor(dv, off);
            }
            if (fr == 0) {
                int rr = bm + wm + i * 16 + kq * 4 + rg;
                if (rr < M) {
                    atomicAdd(&ssrc[rr * 8 + hh], sv);
                    atomicAdd(&sdst[rr * 8 + hh], dv);
                }
            }
        }
}

// ---------------- layer-3 GEMM + scores: N=3, K=512, wave per row ----------------
__global__ __launch_bounds__(256) void k_gemm_n3s(const float* __restrict__ A, const float* __restrict__ W,
                                                  const float* __restrict__ as3, const float* __restrict__ ad3,
                                                  float* __restrict__ C3, float* __restrict__ ssrc,
                                                  float* __restrict__ sdst, int M, int K) {
    __shared__ float lw[1536];
    int t = threadIdx.x;
    for (int i = t; i < K * 3; i += 256) lw[i] = W[i];
    __syncthreads();
    int lane = t & 63;
    int n = blockIdx.x * 4 + (t >> 6);
    if (n >= M) return;
    float a0 = 0.f, a1 = 0.f, a2 = 0.f;
    for (int c = lane; c < K; c += 64) {
        float v = A[(size_t)n * K + c];
        a0 += v * lw[c * 3 + 0];
        a1 += v * lw[c * 3 + 1];
        a2 += v * lw[c * 3 + 2];
    }
    #pragma unroll
    for (int off = 32; off > 0; off >>= 1) {
        a0 += __shfl_xor(a0, off);
        a1 += __shfl_xor(a1, off);
        a2 += __shfl_xor(a2, off);
    }
    if (lane == 0) {
        C3[n * 3 + 0] = a0; C3[n * 3 + 1] = a1; C3[n * 3 + 2] = a2;
        ssrc[n] = a0 * as3[0] + a1 * as3[1] + a2 * as3[2];
        sdst[n] = a0 * ad3[0] + a1 * ad3[1] + a2 * ad3[2];
    }
}

// ---------------- segmented softmax stats only: thread per (n,h) -> mx, inv ----------------
template<int H>
__global__ void k_edge_soft(const float* __restrict__ ssrc, const float* __restrict__ sdst,
                            const int* __restrict__ col, const int* __restrict__ row_off,
                            float* __restrict__ mxp, float* __restrict__ inv, int Nn) {
    int p = blockIdx.x * blockDim.x + threadIdx.x;
    if (p >= Nn * H) return;
    int n = p / H, hh = p - n * H;
    int beg = row_off[n], end = row_off[n + 1];
    float sd = sdst[p];
    float mx = -1e30f;
    for (int j = beg; j < end; j++) {
        float s = ssrc[col[j] * H + hh] + sd;
        s = (s >= 0.f) ? s : NEG_SLOPE * s;
        mx = fmaxf(mx, s);
    }
    float den = 0.f;
    for (int j = beg; j < end; j++) {
        float s = ssrc[col[j] * H + hh] + sd;
        s = (s >= 0.f) ? s : NEG_SLOPE * s;
        den += __expf(s - mx);
    }
    mxp[p] = mx;
    inv[p] = 1.f / (den + EPS_DEN);
}

// ---------------- aggregation from bf16 h, alpha recomputed inline ----------------
// NSPLIT blocks per node, each covers D/NSPLIT cols. BFOUT: write bf16, else f32.
template<int H, int C, int NSPLIT, bool ELU, bool BFOUT>
__global__ __launch_bounds__(256) void k_agg_bf(const unsigned short* __restrict__ hsrc,
                                                const float* __restrict__ ssrc,
                                                const float* __restrict__ sdst,
                                                const float* __restrict__ mxp,
                                                const float* __restrict__ inv,
                                                const int* __restrict__ col,
                                                const int* __restrict__ row_off,
                                                const float* __restrict__ bias,
                                                float* __restrict__ out,
                                                unsigned short* __restrict__ osp) {
    constexpr int D = H * C;
    constexpr int DB = D / NSPLIT;
    constexpr int VEC = DB / 256;
    int n = blockIdx.x / NSPLIT, g = blockIdx.x % NSPLIT;
    int t = threadIdx.x;
    int col0 = g * DB;
    int head = (col0 + VEC * t) / C;
    int beg = row_off[n], end = row_off[n + 1];
    __shared__ int s_col[32];
    __shared__ float s_ex[32 * H];
    __shared__ float sh_mx[H], sh_sd[H];
    if (t < H) { sh_mx[t] = mxp[n * H + t]; sh_sd[t] = sdst[n * H + t]; }
    float acc[VEC];
    #pragma unroll
    for (int v = 0; v < VEC; v++) acc[v] = 0.f;

    for (int j0 = beg; j0 < end; j0 += 32) {
        int nb = min(32, end - j0);
        __syncthreads();
        if (t < nb) s_col[t] = col[j0 + t];
        if (t < nb * H) {
            int e = t >> 3, hh = t & 7;
            int cj = col[j0 + e];
            float s = ssrc[cj * H + hh] + sh_sd[hh];
            s = (s >= 0.f) ? s : NEG_SLOPE * s;
            s_ex[t] = __expf(s - sh_mx[hh]);
        }
        __syncthreads();
        for (int i = 0; i < nb; i++) {
            const unsigned short* hp = hsrc + (size_t)s_col[i] * D + col0 + VEC * t;
            float a = s_ex[i * H + head];
            if (VEC == 4) {
                uint2 u = *(const uint2*)hp;
                acc[0] += a * bflo(u.x);
                acc[1] += a * bfhi(u.x);
                acc[2] += a * bflo(u.y);
                acc[3] += a * bfhi(u.y);
            } else {
                unsigned u = *(const unsigned*)hp;
                acc[0] += a * bflo(u);
                acc[1] += a * bfhi(u);
            }
        }
    }
    float iv = inv[n * H + head];
    #pragma unroll
    for (int v = 0; v < VEC; v++) {
        int idx = col0 + VEC * t + v;
        float val = acc[v] * iv + bias[idx];
        if (ELU) val = (val > 0.f) ? val : (__expf(val) - 1.f);
        if (BFOUT) osp[(size_t)n * D + idx] = f2bf(val);
        else       out[(size_t)n * D + idx] = val;
    }
}

// ---------------- fused layer-3: segment softmax + aggregation + log_softmax ----------------
__global__ void k_l3_fused(const float* __restrict__ h3, const float* __restrict__ ssrc,
                           const float* __restrict__ sdst, const int* __restrict__ col,
                           const int* __restrict__ row_off, const float* __restrict__ b3,
                           float* __restrict__ out, int Nn) {
    int n = blockIdx.x * blockDim.x + threadIdx.x;
    if (n >= Nn) return;
    int beg = row_off[n], end = row_off[n + 1];
    float sd = sdst[n];
    float mx = -1e30f;
    for (int j = beg; j < end; j++) {
        float s = ssrc[col[j]] + sd;
        s = (s >= 0.f) ? s : NEG_SLOPE * s;
        mx = fmaxf(mx, s);
    }
    float den = 0.f, a0 = 0.f, a1 = 0.f, a2 = 0.f;
    for (int j = beg; j < end; j++) {
        int sI = col[j];
        float s = ssrc[sI] + sd;
        s = (s >= 0.f) ? s : NEG_SLOPE * s;
        float ex = __expf(s - mx);
        den += ex;
        a0 += ex * h3[sI * 3 + 0];
        a1 += ex * h3[sI * 3 + 1];
        a2 += ex * h3[sI * 3 + 2];
    }
    float iv = 1.f / (den + EPS_DEN);
    float v0 = a0 * iv + b3[0], v1 = a1 * iv + b3[1], v2 = a2 * iv + b3[2];
    float m = fmaxf(v0, fmaxf(v1, v2));
    float l = logf(__expf(v0 - m) + __expf(v1 - m) + __expf(v2 - m));
    out[n * 3 + 0] = v0 - m - l;
    out[n * 3 + 1] = v1 - m - l;
    out[n * 3 + 2] = v2 - m - l;
}

extern "C" void kernel_launch(void* const* d_in, const int* in_sizes, int n_in,
                              void* d_out, int out_size, void* d_ws, size_t ws_size,
                              hipStream_t stream) {
    (void)n_in; (void)out_size; (void)ws_size;
    const float* x   = (const float*)d_in[0];
    const int*   ei  = (const int*)d_in[1];
    const float* W1  = (const float*)d_in[2];
    const float* as1 = (const float*)d_in[3];
    const float* ad1 = (const float*)d_in[4];
    const float* b1  = (const float*)d_in[5];
    const float* W2  = (const float*)d_in[6];
    const float* as2 = (const float*)d_in[7];
    const float* ad2 = (const float*)d_in[8];
    const float* b2  = (const float*)d_in[9];
    const float* W3  = (const float*)d_in[10];
    const float* as3 = (const float*)d_in[11];
    const float* ad3 = (const float*)d_in[12];
    const float* b3  = (const float*)d_in[13];
    float* out = (float*)d_out;

    const int Nn = in_sizes[0] / 64;   // 10000
    const int E  = in_sizes[1] / 2;    // 160000
    const int ET = E + Nn;
    const int Mp = ((Nn + 127) / 128) * 128;   // 10112

    char* ws = (char*)d_ws;
    size_t off = 0;
    auto alloc = [&](size_t bytes) -> void* {
        void* p = ws + off;
        off = (off + bytes + 255) & ~(size_t)255;
        return p;
    };
    unsigned short* hbuf = (unsigned short*)alloc((size_t)Mp * 1024 * 2);
    // union: A2 bf16 [Mp,1024] (L1 agg out -> L2 GEMM A), later obuf f32 [Nn,512]
    void*  big  = alloc((size_t)Mp * 1024 * 2 + 65536);
    unsigned short* A2 = (unsigned short*)big;
    float* obuf = (float*)big;
    float* h3   = (float*)alloc((size_t)Nn * 3 * 4);
    short* A1   = (short*)alloc((size_t)Mp * 128 * 2);
    short* B1t  = (short*)alloc((size_t)1024 * 128 * 2);
    short* B2t  = (short*)alloc((size_t)512 * 1024 * 2);
    float* mxp  = (float*)alloc((size_t)Nn * 8 * 4);
    float* inv  = (float*)alloc((size_t)Nn * 8 * 4);
    // zero region: counts, cursor, ssrc1, sdst1, ssrc2, sdst2
    int* zbase  = (int*)alloc((size_t)Nn * 34 * 4);
    int* counts = zbase;
    int* cursor = counts + Nn;
    float* ssrc1 = (float*)(cursor + Nn);
    float* sdst1 = ssrc1 + (size_t)Nn * 8;
    float* ssrc2 = sdst1 + (size_t)Nn * 8;
    float* sdst2 = ssrc2 + (size_t)Nn * 8;
    int* row_off= (int*)alloc((size_t)(Nn + 1) * 4);
    int* colb   = (int*)alloc((size_t)ET * 4);

    hipMemsetAsync(zbase, 0, (size_t)Nn * 34 * 4, stream);

    int etb = (ET + 255) / 256;
    k_count<<<etb, 256, 0, stream>>>(ei, E, Nn, counts);
    k_scan<<<1, 256, 0, stream>>>(counts, Nn, ET, row_off);
    k_scatter<<<etb, 256, 0, stream>>>(ei, E, Nn, row_off, cursor, colb);

    k_split_x<<<(Mp * 64 + 255) / 256, 256, 0, stream>>>(x, A1, Nn, Mp, 64);
    k_split_wt<<<dim3(64 / 32, 1024 / 32), 256, 0, stream>>>(W1, B1t, 64, 1024, 1);
    k_split_wt<<<dim3(1024 / 32, 512 / 32), 256, 0, stream>>>(W2, B2t, 1024, 512, 0);

    // ---- layer 1: 64 -> 8x128 concat (A split 2-term, scores fused) ----
    {
        int nb = (1024 / 64) * (Mp / 64);
        k_mfma64<<<nb, 256, 0, stream>>>(A1 /*short*/, B1t, hbuf, as1, ad1, ssrc1, sdst1,
                                         Nn, 1024, 128, 128, 128, 7);
        int nw = Nn * 8;
        k_edge_soft<8><<<(nw + 255) / 256, 256, 0, stream>>>(ssrc1, sdst1, colb, row_off, mxp, inv, Nn);
        k_agg_bf<8, 128, 2, true, true><<<Nn * 2, 256, 0, stream>>>(hbuf, ssrc1, sdst1, mxp, inv,
                                                                    colb, row_off, b1, nullptr, A2);
    }
    // ---- layer 2: 1024 -> 8x64 concat (plain bf16 GEMM, scores fused) ----
    {
        int nb = (512 / 64) * (Mp / 64);
        k_mfma64<<<nb, 256, 0, stream>>>((const short*)A2, B2t, hbuf, as2, ad2, ssrc2, sdst2,
                                         Nn, 512, 1024, 1024, 1024, 6);
        int nw = Nn * 8;
        k_edge_soft<8><<<(nw + 255) / 256, 256, 0, stream>>>(ssrc2, sdst2, colb, row_off, mxp, inv, Nn);
        k_agg_bf<8, 64, 1, true, false><<<Nn, 256, 0, stream>>>(hbuf, ssrc2, sdst2, mxp, inv,
                                                                colb, row_off, b2, obuf, nullptr);
    }
    // ---- layer 3: 512 -> 1x3, mean + log_softmax (fused) ----
    {
        k_gemm_n3s<<<(Nn + 3) / 4, 256, 0, stream>>>(obuf, W3, as3, ad3, h3, ssrc1, sdst1, Nn, 512);
        k_l3_fused<<<(Nn + 255) / 256, 256, 0, stream>>>(h3, ssrc1, sdst1, colb, row_off, b3, out, Nn);
    }
}

// Round 8
// 198.949 us; speedup vs baseline: 1.4432x; 1.4432x over previous
//
#include <hip/hip_runtime.h>
#include <math.h>

#define NEG_SLOPE 0.2f
#define EPS_DEN 1e-16f

typedef __attribute__((ext_vector_type(8))) short bf16x8;
typedef __attribute__((ext_vector_type(4))) float f32x4;

__device__ inline void split2(float a, short& hi, short& lo) {
    unsigned u = __float_as_uint(a);
    unsigned uh = (u + 0x8000u) & 0xFFFF0000u;
    float fh = __uint_as_float(uh);
    hi = (short)(uh >> 16);
    float r = a - fh;
    lo = (short)((__float_as_uint(r) + 0x8000u) >> 16);
}

__device__ inline unsigned short f2bf(float f) {   // RNE
    unsigned u = __float_as_uint(f);
    return (unsigned short)((u + 0x7FFFu + ((u >> 16) & 1u)) >> 16);
}
__device__ inline float bflo(unsigned u) { return __uint_as_float(u << 16); }
__device__ inline float bfhi(unsigned u) { return __uint_as_float(u & 0xFFFF0000u); }

// ---------------- CSR build ----------------
__global__ void k_count(const int* __restrict__ ei, int E, int Nn, int* counts) {
    int e = blockIdx.x * blockDim.x + threadIdx.x;
    int ET = E + Nn;
    if (e >= ET) return;
    int d = (e < E) ? ei[E + e] : (e - E);
    atomicAdd(&counts[d], 1);
}

__global__ void k_scan(const int* __restrict__ counts, int Nn, int ET, int* __restrict__ row_off) {
    __shared__ int lds[256];
    int t = threadIdx.x;
    int chunk = (Nn + 255) / 256;
    int b0 = t * chunk, b1 = min(Nn, b0 + chunk);
    int s = 0;
    for (int i = b0; i < b1; i++) s += counts[i];
    lds[t] = s;
    __syncthreads();
    if (t == 0) {
        int run = 0;
        for (int i = 0; i < 256; i++) { int v = lds[i]; lds[i] = run; run += v; }
    }
    __syncthreads();
    int run = lds[t];
    for (int i = b0; i < b1; i++) { row_off[i] = run; run += counts[i]; }
    if (t == 0) row_off[Nn] = ET;
}

__global__ void k_scatter(const int* __restrict__ ei, int E, int Nn,
                          const int* __restrict__ row_off, int* cursor, int* __restrict__ col) {
    int e = blockIdx.x * blockDim.x + threadIdx.x;
    int ET = E + Nn;
    if (e >= ET) return;
    int d = (e < E) ? ei[E + e] : (e - E);
    int s = (e < E) ? ei[e] : (e - E);
    int pos = atomicAdd(&cursor[d], 1);
    col[row_off[d] + pos] = s;
}

// ---------------- split conversions ----------------
__global__ void k_split_x(const float* __restrict__ x, short* __restrict__ A,
                          int M, int Mp, int K) {
    int i = blockIdx.x * blockDim.x + threadIdx.x;
    if (i >= Mp * K) return;
    int row = i / K, c = i - row * K;
    float v = (row < M) ? x[(size_t)row * K + c] : 0.f;
    short hi, lo;
    split2(v, hi, lo);
    A[(size_t)row * (2 * K) + c] = hi;
    A[(size_t)row * (2 * K) + K + c] = lo;
}

// W [K,N] f32 -> Bt [N, (1+dup)K] bf16 (transposed; dup=1 writes [hi|hi] for split-A GEMM)
__global__ __launch_bounds__(256) void k_split_wt(const float* __restrict__ W,
                                                  short* __restrict__ Bt, int K, int N, int dup) {
    __shared__ float s[32][33];
    int k0 = blockIdx.x * 32, n0 = blockIdx.y * 32;
    int tx = threadIdx.x & 31, ty = threadIdx.x >> 5;
    for (int r = ty; r < 32; r += 8) s[r][tx] = W[(size_t)(k0 + r) * N + n0 + tx];
    __syncthreads();
    int ldbt = (1 + dup) * K;
    for (int r = ty; r < 32; r += 8) {
        float v = s[tx][r];
        unsigned u = __float_as_uint(v);
        short hi = (short)((u + 0x7FFFu + ((u >> 16) & 1u)) >> 16);
        size_t base = (size_t)(n0 + r) * ldbt + k0 + tx;
        Bt[base] = hi;
        if (dup) Bt[base + K] = hi;
    }
}

// ---------------- MFMA bf16 GEMM, 64x64 tile, BK=32, XCD-grouped, swizzled LDS ----------------
__global__ __launch_bounds__(256) void k_mfma64(const short* __restrict__ A,
                                                const short* __restrict__ B,
                                                unsigned short* __restrict__ C,
                                                int M, int N, int Ktot,
                                                int lda, int ldb) {
    __shared__ short As[64 * 32];
    __shared__ short Bs[64 * 32];
    int t = threadIdx.x;
    int lane = t & 63;
    int wid = t >> 6;

    int nbx = N >> 6;
    int nb = gridDim.x;
    int q = nb >> 3, r = nb & 7;
    int xcd = blockIdx.x & 7, pos = blockIdx.x >> 3;
    int L = (xcd < r ? xcd * (q + 1) : r * (q + 1) + (xcd - r) * q) + pos;
    int bn = (L % nbx) * 64;
    int bm = (L / nbx) * 64;

    int wm = (wid >> 1) * 32, wn = (wid & 1) * 32;
    int fr = lane & 15, kq = lane >> 4;

    int srow = t >> 2, sslot = t & 3;
    int sko = ((sslot ^ ((srow >> 1) & 3)) << 3);

    f32x4 acc[2][2] = {};

    for (int k0 = 0; k0 < Ktot; k0 += 32) {
        {
            const short* sa = A + (size_t)(bm + srow) * lda + k0 + sko;
            const short* sb = B + (size_t)(bn + srow) * ldb + k0 + sko;
            short* da = As + (size_t)(wid << 6) * 8;
            short* db = Bs + (size_t)(wid << 6) * 8;
            __builtin_amdgcn_global_load_lds((const __attribute__((address_space(1))) void*)sa,
                                             (__attribute__((address_space(3))) void*)da, 16, 0, 0);
            __builtin_amdgcn_global_load_lds((const __attribute__((address_space(1))) void*)sb,
                                             (__attribute__((address_space(3))) void*)db, 16, 0, 0);
        }
        __syncthreads();
        bf16x8 af[2], bfv[2];
        #pragma unroll
        for (int i = 0; i < 2; i++) {
            int rowa = wm + i * 16 + fr;
            int rowb = wn + i * 16 + fr;
            af[i]  = *(const bf16x8*)(As + rowa * 32 + ((kq ^ ((rowa >> 1) & 3)) << 3));
            bfv[i] = *(const bf16x8*)(Bs + rowb * 32 + ((kq ^ ((rowb >> 1) & 3)) << 3));
        }
        #pragma unroll
        for (int i = 0; i < 2; i++)
            #pragma unroll
            for (int j = 0; j < 2; j++)
                acc[i][j] = __builtin_amdgcn_mfma_f32_16x16x32_bf16(af[i], bfv[j], acc[i][j], 0, 0, 0);
        __syncthreads();
    }
    #pragma unroll
    for (int i = 0; i < 2; i++) {
        int rbase = bm + wm + i * 16 + kq * 4;
        #pragma unroll
        for (int j = 0; j < 2; j++) {
            int colc = bn + wn + j * 16 + fr;
            #pragma unroll
            for (int rg = 0; rg < 4; rg++) {
                int rr = rbase + rg;
                if (rr < M) C[(size_t)rr * N + colc] = f2bf(acc[i][j][rg]);
            }
        }
    }
}

// ---------------- scores: wave per node, 8-lane head groups ----------------
template<int H, int C>
__global__ __launch_bounds__(256) void k_scores_bf(const unsigned short* __restrict__ h,
                                                   const float* __restrict__ a_src,
                                                   const float* __restrict__ a_dst,
                                                   float* __restrict__ ssrc,
                                                   float* __restrict__ sdst, int Nn) {
    constexpr int D = H * C;
    constexpr int PER = D / 64;      // elems per lane (16 or 8)
    constexpr int GRP = C / PER;     // lanes per head (8)
    int lane = threadIdx.x & 63;
    int n = blockIdx.x * 4 + (threadIdx.x >> 6);
    if (n >= Nn) return;
    const unsigned short* hp = h + (size_t)n * D + lane * PER;
    int cb = lane * PER;
    float as = 0.f, ad = 0.f;
    #pragma unroll
    for (int j0 = 0; j0 < PER; j0 += 8) {
        uint4 u = *(const uint4*)(hp + j0);
        int c = cb + j0;
        as += bflo(u.x) * a_src[c + 0] + bfhi(u.x) * a_src[c + 1]
            + bflo(u.y) * a_src[c + 2] + bfhi(u.y) * a_src[c + 3]
            + bflo(u.z) * a_src[c + 4] + bfhi(u.z) * a_src[c + 5]
            + bflo(u.w) * a_src[c + 6] + bfhi(u.w) * a_src[c + 7];
        ad += bflo(u.x) * a_dst[c + 0] + bfhi(u.x) * a_dst[c + 1]
            + bflo(u.y) * a_dst[c + 2] + bfhi(u.y) * a_dst[c + 3]
            + bflo(u.z) * a_dst[c + 4] + bfhi(u.z) * a_dst[c + 5]
            + bflo(u.w) * a_dst[c + 6] + bfhi(u.w) * a_dst[c + 7];
    }
    #pragma unroll
    for (int off = GRP >> 1; off >= 1; off >>= 1) {
        as += __shfl_xor(as, off);
        ad += __shfl_xor(ad, off);
    }
    if ((lane & (GRP - 1)) == 0) {
        int hh = lane / GRP;
        ssrc[n * H + hh] = as;
        sdst[n * H + hh] = ad;
    }
}

// ---------------- layer-3 GEMM + scores: N=3, K=512, wave per row ----------------
__global__ __launch_bounds__(256) void k_gemm_n3s(const float* __restrict__ A, const float* __restrict__ W,
                                                  const float* __restrict__ as3, const float* __restrict__ ad3,
                                                  float* __restrict__ C3, float* __restrict__ ssrc,
                                                  float* __restrict__ sdst, int M, int K) {
    __shared__ float lw[1536];
    int t = threadIdx.x;
    for (int i = t; i < K * 3; i += 256) lw[i] = W[i];
    __syncthreads();
    int lane = t & 63;
    int n = blockIdx.x * 4 + (t >> 6);
    if (n >= M) return;
    float a0 = 0.f, a1 = 0.f, a2 = 0.f;
    for (int c = lane; c < K; c += 64) {
        float v = A[(size_t)n * K + c];
        a0 += v * lw[c * 3 + 0];
        a1 += v * lw[c * 3 + 1];
        a2 += v * lw[c * 3 + 2];
    }
    #pragma unroll
    for (int off = 32; off > 0; off >>= 1) {
        a0 += __shfl_xor(a0, off);
        a1 += __shfl_xor(a1, off);
        a2 += __shfl_xor(a2, off);
    }
    if (lane == 0) {
        C3[n * 3 + 0] = a0; C3[n * 3 + 1] = a1; C3[n * 3 + 2] = a2;
        ssrc[n] = a0 * as3[0] + a1 * as3[1] + a2 * as3[2];
        sdst[n] = a0 * ad3[0] + a1 * ad3[1] + a2 * ad3[2];
    }
}

// ---------------- aggregation from bf16 h: softmax (no max-shift) + den fused inline ----------------
template<int H, int C, bool ELU, bool BFOUT>
__global__ __launch_bounds__(256) void k_agg_bf(const unsigned short* __restrict__ hsrc,
                                                const float* __restrict__ ssrc,
                                                const float* __restrict__ sdst,
                                                const int* __restrict__ col,
                                                const int* __restrict__ row_off,
                                                const float* __restrict__ bias,
                                                float* __restrict__ out,
                                                unsigned short* __restrict__ osp) {
    constexpr int D = H * C;
    constexpr int VEC = D / 256;
    int n = blockIdx.x, t = threadIdx.x;
    int head = (VEC * t) / C;
    int beg = row_off[n], end = row_off[n + 1];
    __shared__ int s_col[32];
    __shared__ float s_ex[32 * H];
    __shared__ float sh_sd[H];
    if (t < H) sh_sd[t] = sdst[n * H + t];
    float acc[VEC];
    float den = 0.f;
    #pragma unroll
    for (int v = 0; v < VEC; v++) acc[v] = 0.f;

    for (int j0 = beg; j0 < end; j0 += 32) {
        int nb = min(32, end - j0);
        __syncthreads();
        if (t < nb) s_col[t] = col[j0 + t];
        if (t < nb * H) {
            int e = t >> 3, hh = t & 7;
            int cj = col[j0 + e];
            float s = ssrc[cj * H + hh] + sh_sd[hh];
            s = (s >= 0.f) ? s : NEG_SLOPE * s;
            s_ex[t] = __expf(s);
        }
        __syncthreads();
        for (int i = 0; i < nb; i++) {
            const unsigned short* hp = hsrc + (size_t)s_col[i] * D + VEC * t;
            float a = s_ex[i * H + head];
            den += a;
            if (VEC == 4) {
                uint2 u = *(const uint2*)hp;
                acc[0] += a * bflo(u.x);
                acc[1] += a * bfhi(u.x);
                acc[2] += a * bflo(u.y);
                acc[3] += a * bfhi(u.y);
            } else {
                unsigned u = *(const unsigned*)hp;
                acc[0] += a * bflo(u);
                acc[1] += a * bfhi(u);
            }
        }
    }
    float iv = 1.f / (den + EPS_DEN);
    #pragma unroll
    for (int v = 0; v < VEC; v++) {
        int idx = VEC * t + v;
        float val = acc[v] * iv + bias[idx];
        if (ELU) val = (val > 0.f) ? val : (__expf(val) - 1.f);
        if (BFOUT) osp[(size_t)n * D + idx] = f2bf(val);
        else       out[(size_t)n * D + idx] = val;
    }
}

// ---------------- fused layer-3: softmax (no shift) + aggregation + log_softmax ----------------
__global__ void k_l3_fused(const float* __restrict__ h3, const float* __restrict__ ssrc,
                           const float* __restrict__ sdst, const int* __restrict__ col,
                           const int* __restrict__ row_off, const float* __restrict__ b3,
                           float* __restrict__ out, int Nn) {
    int n = blockIdx.x * blockDim.x + threadIdx.x;
    if (n >= Nn) return;
    int beg = row_off[n], end = row_off[n + 1];
    float sd = sdst[n];
    float den = 0.f, a0 = 0.f, a1 = 0.f, a2 = 0.f;
    for (int j = beg; j < end; j++) {
        int sI = col[j];
        float s = ssrc[sI] + sd;
        s = (s >= 0.f) ? s : NEG_SLOPE * s;
        float ex = __expf(s);
        den += ex;
        a0 += ex * h3[sI * 3 + 0];
        a1 += ex * h3[sI * 3 + 1];
        a2 += ex * h3[sI * 3 + 2];
    }
    float iv = 1.f / (den + EPS_DEN);
    float v0 = a0 * iv + b3[0], v1 = a1 * iv + b3[1], v2 = a2 * iv + b3[2];
    float m = fmaxf(v0, fmaxf(v1, v2));
    float l = logf(__expf(v0 - m) + __expf(v1 - m) + __expf(v2 - m));
    out[n * 3 + 0] = v0 - m - l;
    out[n * 3 + 1] = v1 - m - l;
    out[n * 3 + 2] = v2 - m - l;
}

extern "C" void kernel_launch(void* const* d_in, const int* in_sizes, int n_in,
                              void* d_out, int out_size, void* d_ws, size_t ws_size,
                              hipStream_t stream) {
    (void)n_in; (void)out_size; (void)ws_size;
    const float* x   = (const float*)d_in[0];
    const int*   ei  = (const int*)d_in[1];
    const float* W1  = (const float*)d_in[2];
    const float* as1 = (const float*)d_in[3];
    const float* ad1 = (const float*)d_in[4];
    const float* b1  = (const float*)d_in[5];
    const float* W2  = (const float*)d_in[6];
    const float* as2 = (const float*)d_in[7];
    const float* ad2 = (const float*)d_in[8];
    const float* b2  = (const float*)d_in[9];
    const float* W3  = (const float*)d_in[10];
    const float* as3 = (const float*)d_in[11];
    const float* ad3 = (const float*)d_in[12];
    const float* b3  = (const float*)d_in[13];
    float* out = (float*)d_out;

    const int Nn = in_sizes[0] / 64;   // 10000
    const int E  = in_sizes[1] / 2;    // 160000
    const int ET = E + Nn;
    const int Mp = ((Nn + 127) / 128) * 128;   // 10112

    char* ws = (char*)d_ws;
    size_t off = 0;
    auto alloc = [&](size_t bytes) -> void* {
        void* p = ws + off;
        off = (off + bytes + 255) & ~(size_t)255;
        return p;
    };
    unsigned short* hbuf = (unsigned short*)alloc((size_t)Mp * 1024 * 2);
    // union: A2 bf16 [Mp,1024] (L1 agg out -> L2 GEMM A), later obuf f32 [Nn,512]
    void*  big  = alloc((size_t)Mp * 1024 * 2 + 65536);
    unsigned short* A2 = (unsigned short*)big;
    float* obuf = (float*)big;
    float* h3   = (float*)alloc((size_t)Nn * 3 * 4);
    short* A1   = (short*)alloc((size_t)Mp * 128 * 2);
    short* B1t  = (short*)alloc((size_t)1024 * 128 * 2);
    short* B2t  = (short*)alloc((size_t)512 * 1024 * 2);
    float* ssrc = (float*)alloc((size_t)Nn * 8 * 4);
    float* sdst = (float*)alloc((size_t)Nn * 8 * 4);
    int* counts = (int*)alloc((size_t)Nn * 2 * 4);   // counts + cursor contiguous
    int* cursor = counts + Nn;
    int* row_off= (int*)alloc((size_t)(Nn + 1) * 4);
    int* colb   = (int*)alloc((size_t)ET * 4);

    hipMemsetAsync(counts, 0, (size_t)Nn * 2 * 4, stream);

    int etb = (ET + 255) / 256;
    k_count<<<etb, 256, 0, stream>>>(ei, E, Nn, counts);
    k_scan<<<1, 256, 0, stream>>>(counts, Nn, ET, row_off);
    k_scatter<<<etb, 256, 0, stream>>>(ei, E, Nn, row_off, cursor, colb);

    k_split_x<<<(Mp * 64 + 255) / 256, 256, 0, stream>>>(x, A1, Nn, Mp, 64);
    k_split_wt<<<dim3(64 / 32, 1024 / 32), 256, 0, stream>>>(W1, B1t, 64, 1024, 1);
    k_split_wt<<<dim3(1024 / 32, 512 / 32), 256, 0, stream>>>(W2, B2t, 1024, 512, 0);

    // ---- layer 1: 64 -> 8x128 concat (A split 2-term) ----
    {
        int nb = (1024 / 64) * (Mp / 64);
        k_mfma64<<<nb, 256, 0, stream>>>(A1, B1t, hbuf, Nn, 1024, 128, 128, 128);
        k_scores_bf<8, 128><<<(Nn + 3) / 4, 256, 0, stream>>>(hbuf, as1, ad1, ssrc, sdst, Nn);
        k_agg_bf<8, 128, true, true><<<Nn, 256, 0, stream>>>(hbuf, ssrc, sdst, colb, row_off, b1, nullptr, A2);
    }
    // ---- layer 2: 1024 -> 8x64 concat (plain bf16 GEMM) ----
    {
        int nb = (512 / 64) * (Mp / 64);
        k_mfma64<<<nb, 256, 0, stream>>>((const short*)A2, B2t, hbuf, Nn, 512, 1024, 1024, 1024);
        k_scores_bf<8, 64><<<(Nn + 3) / 4, 256, 0, stream>>>(hbuf, as2, ad2, ssrc, sdst, Nn);
        k_agg_bf<8, 64, true, false><<<Nn, 256, 0, stream>>>(hbuf, ssrc, sdst, colb, row_off, b2, obuf, nullptr);
    }
    // ---- layer 3: 512 -> 1x3, mean + log_softmax (fused) ----
    {
        k_gemm_n3s<<<(Nn + 3) / 4, 256, 0, stream>>>(obuf, W3, as3, ad3, h3, ssrc, sdst, Nn, 512);
        k_l3_fused<<<(Nn + 255) / 256, 256, 0, stream>>>(h3, ssrc, sdst, colb, row_off, b3, out, Nn);
    }
}